// Round 5
// baseline (458.344 us; speedup 1.0000x reference)
//
#include <hip/hip_runtime.h>
#include <math.h>

#define BSZ 256
#define DIM 1024
#define VOC 50257
#define NL 2
#define NB 8
#define DH 128

typedef __bf16 bf16x8 __attribute__((ext_vector_type(8)));
typedef float  f32x4  __attribute__((ext_vector_type(4)));
typedef unsigned short u16;
typedef unsigned int u32;
typedef u16 u16x8 __attribute__((ext_vector_type(8)));

__device__ __forceinline__ u16 f2bf(float f) {
  unsigned int u = __float_as_uint(f);
  u += 0x7fffu + ((u >> 16) & 1u);   // RNE
  return (u16)(u >> 16);
}
__device__ __forceinline__ float sigm(float x) { return 1.0f / (1.0f + __expf(-x)); }

// f32x8 -> bf16x8, hardware RNE (bit-identical to f2bf)
__device__ __forceinline__ bf16x8 cvt8(float4 a, float4 b) {
  bf16x8 r;
  r[0] = (__bf16)a.x; r[1] = (__bf16)a.y; r[2] = (__bf16)a.z; r[3] = (__bf16)a.w;
  r[4] = (__bf16)b.x; r[5] = (__bf16)b.y; r[6] = (__bf16)b.z; r[7] = (__bf16)b.w;
  return r;
}

// async global->LDS DMA, 16 B per lane; lds dst is wave-uniform base (+lane*16 by HW)
__device__ __forceinline__ void gld16(const float* g, float* l) {
  __builtin_amdgcn_global_load_lds(
      (const __attribute__((address_space(1))) u32*)(g),
      (__attribute__((address_space(3))) u32*)(l), 16, 0, 0);
}

// ---------------------------------------------------------------------------
// Barrier-free per-wave GEMM: acc[M16][N16] += A(bf16, row-major lda) *
// B(fp32, row-major ldb)^T. Fragments loaded directly from global in MFMA
// operand layout. 4-stage register pipeline. Requires K % 128 == 0.
// ---------------------------------------------------------------------------
template<int M16, int N16, int K, bool CLAMPN>
__device__ __forceinline__ void wave_gemm(
    const u16* __restrict__ A, int lda,
    const float* __restrict__ B, int ldb, int nClamp,
    f32x4 (&acc)[M16][N16])
{
  const int lane = threadIdx.x & 63;
  const int quad = lane >> 4;
  const int l16  = lane & 15;

  const u16* aR[M16];
  const float* bR[N16];
#pragma unroll
  for (int mi = 0; mi < M16; ++mi)
    aR[mi] = A + (long)(mi * 16 + l16) * lda + quad * 8;
#pragma unroll
  for (int ni = 0; ni < N16; ++ni) {
    int n = ni * 16 + l16;
    if (CLAMPN) n = n > nClamp ? nClamp : n;   // clamp addr; result discarded
    bR[ni] = B + (long)n * ldb + quad * 8;
  }

  bf16x8 aF[4][M16];
  bf16x8 bF[4][N16];

#define WG_LOAD(kk, buf)                                                  \
  {                                                                       \
    _Pragma("unroll")                                                     \
    for (int ni = 0; ni < N16; ++ni) {                                    \
      float4 v0 = *(const float4*)(bR[ni] + (kk));                        \
      float4 v1 = *(const float4*)(bR[ni] + (kk) + 4);                    \
      u16x8 h;                                                            \
      h[0] = f2bf(v0.x); h[1] = f2bf(v0.y);                               \
      h[2] = f2bf(v0.z); h[3] = f2bf(v0.w);                               \
      h[4] = f2bf(v1.x); h[5] = f2bf(v1.y);                               \
      h[6] = f2bf(v1.z); h[7] = f2bf(v1.w);                               \
      bF[buf][ni] = __builtin_bit_cast(bf16x8, h);                        \
    }                                                                     \
    _Pragma("unroll")                                                     \
    for (int mi = 0; mi < M16; ++mi)                                      \
      aF[buf][mi] = *(const bf16x8*)(aR[mi] + (kk));                      \
  }

#define WG_MM(buf)                                                        \
  {                                                                       \
    _Pragma("unroll")                                                     \
    for (int mi = 0; mi < M16; ++mi)                                      \
      _Pragma("unroll")                                                   \
      for (int ni = 0; ni < N16; ++ni)                                    \
        acc[mi][ni] = __builtin_amdgcn_mfma_f32_16x16x32_bf16(            \
            aF[buf][mi], bF[buf][ni], acc[mi][ni], 0, 0, 0);              \
  }

  WG_LOAD(0, 0);
  WG_LOAD(32, 1);
  WG_LOAD(64, 2);
#pragma unroll 1
  for (int kk = 0; kk < K - 128; kk += 128) {
    WG_LOAD(kk + 96, 3);  WG_MM(0);
    WG_LOAD(kk + 128, 0); WG_MM(1);
    WG_LOAD(kk + 160, 1); WG_MM(2);
    WG_LOAD(kk + 192, 2); WG_MM(3);
  }
  WG_LOAD(K - 32, 3);
  WG_MM(0); WG_MM(1); WG_MM(2); WG_MM(3);
#undef WG_LOAD
#undef WG_MM
}

#define ACC_DECL(N16V)                                \
  f32x4 acc[4][N16V];                                 \
  { f32x4 z = {0.f, 0.f, 0.f, 0.f};                   \
    _Pragma("unroll")                                 \
    for (int i = 0; i < 4; ++i)                       \
      _Pragma("unroll")                               \
      for (int j = 0; j < N16V; ++j) acc[i][j] = z; }

// ---------------------------------------------------------------------------
// K1: carry (bool-layout detect), x gather, h->bf16, + LLC warm of all weights
// ---------------------------------------------------------------------------
__global__ __launch_bounds__(256) void k_prep(
    const int* __restrict__ ids, const void* __restrict__ mask,
    const float* __restrict__ emb, const float* __restrict__ hstate,
    const float* __restrict__ W_alpha, const float* __restrict__ W_in,
    const float* __restrict__ W_wm_out, const float* __restrict__ W_x,
    const float* __restrict__ W_h, const float* __restrict__ W_wml,
    const float* __restrict__ W_g,
    float* __restrict__ xout, u16* __restrict__ x_bf,
    u16* __restrict__ h_bf, float* __restrict__ carry, float* __restrict__ sink)
{
  __shared__ int sInt;
  const int tid = threadIdx.x, s = blockIdx.x;
  if (tid == 0) sInt = 1;
  __syncthreads();
  if (tid < 64) {
    int v = ((const int*)mask)[tid];
    if (v != 0 && v != 1) atomicAnd(&sInt, 0);
  }
  __syncthreads();
  if (tid == 0) {
    int m = sInt ? ((const int*)mask)[s] : (int)((const unsigned char*)mask)[s];
    carry[s] = m ? 0.0f : 1.0f;
  }
  long id = ids[s];
  int k = tid * 4;
  float4 v = *(const float4*)(emb + id * DIM + k);
  *(float4*)(xout + (long)s * DIM + k) = v;
  ushort4 h; h.x = f2bf(v.x); h.y = f2bf(v.y); h.z = f2bf(v.z); h.w = f2bf(v.w);
  *(ushort4*)(x_bf + (long)s * DIM + k) = h;
#pragma unroll
  for (int l = 0; l < NL; ++l) {
    long off = (long)l * BSZ * DIM + (long)s * DIM + k;
    float4 w = *(const float4*)(hstate + off);
    ushort4 o; o.x = f2bf(w.x); o.y = f2bf(w.y); o.z = f2bf(w.z); o.w = f2bf(w.w);
    *(ushort4*)(h_bf + off) = o;
  }
  // ---- LLC warm (loads can't be eliminated; branch never taken) ----
  long gtid = (long)blockIdx.x * 256 + tid;
  long gstride = (long)gridDim.x * 256;
  float acc = 0.f;
  {
    const long nDD = (long)DIM * DIM / 4;       // 1024x1024 f32 -> float4 count
    for (long i = gtid; i < nDD; i += gstride) {
      float4 a = ((const float4*)W_alpha)[i];
      float4 b = ((const float4*)W_in)[i];
      float4 c = ((const float4*)W_wm_out)[i];
      acc += a.x + a.w + b.x + b.w + c.x + c.w;
    }
    const long nS = (long)NL * NB * DH * DH / 4;
    for (long i = gtid; i < nS; i += gstride) {
      float4 a = ((const float4*)W_x)[i];
      float4 b = ((const float4*)W_h)[i];
      float4 c = ((const float4*)W_g)[i];
      acc += a.x + a.w + b.x + b.w + c.x + c.w;
    }
    const long nW = (long)NL * NB * DH * DIM / 4;
    for (long i = gtid; i < nW; i += gstride) {
      float4 a = ((const float4*)W_wml)[i];
      acc += a.x + a.w;
    }
  }
  if (acc == -1.17521e35f) *sink = acc;   // never true in practice; defeats DCE
}

// ---------------------------------------------------------------------------
// K2: [alpha_pre | x_proj] = x @ [W_alpha ; W_in]^T, fused wm_new epilogue
// 512 blocks x 64 threads: m-slice = blk&3, n-tile16 = blk>>2 (128 tiles)
// ---------------------------------------------------------------------------
__global__ __launch_bounds__(64) void k_gemm1(
    const u16* __restrict__ x_bf,
    const float* __restrict__ W_alpha, const float* __restrict__ W_in,
    const float* __restrict__ carry, const float* __restrict__ wm_state,
    const float* __restrict__ xout,
    u16* __restrict__ wm_bf, u16* __restrict__ cur_bf)
{
  const int tid = threadIdx.x, quad = tid >> 4, l16 = tid & 15;
  const int m = blockIdx.x & 3;
  const int nt = blockIdx.x >> 2;
  const bool isAlpha = nt < 64;
  const int n0 = (isAlpha ? nt : nt - 64) * 16;
  ACC_DECL(1)
  wave_gemm<4, 1, DIM, false>(x_bf + (long)m * 64 * DIM, DIM,
                              (isAlpha ? W_alpha : W_in) + (long)n0 * DIM, DIM, 0, acc);
#pragma unroll
  for (int mi = 0; mi < 4; ++mi) {
    int n = n0 + l16;
#pragma unroll
    for (int r = 0; r < 4; ++r) {
      int s = m * 64 + mi * 16 + quad * 4 + r;
      float c = acc[mi][0][r];
      long idx = (long)s * DIM + n;
      if (isAlpha) wm_bf[idx] = f2bf(carry[s] * sigm(c) * wm_state[idx] + xout[idx]);
      else         cur_bf[idx] = f2bf(c);
    }
  }
}

// ---------------------------------------------------------------------------
// K3: y_wm = tanh(wm_new @ W_wm_out^T)   (256 blocks x 64 threads)
// ---------------------------------------------------------------------------
__global__ __launch_bounds__(64) void k_gemm2(
    const u16* __restrict__ wm_bf, const float* __restrict__ W_wm_out,
    float* __restrict__ yout, u16* __restrict__ ywm_bf)
{
  const int tid = threadIdx.x, quad = tid >> 4, l16 = tid & 15;
  const int m = blockIdx.x & 3;
  const int n0 = (blockIdx.x >> 2) * 16;
  ACC_DECL(1)
  wave_gemm<4, 1, DIM, false>(wm_bf + (long)m * 64 * DIM, DIM,
                              W_wm_out + (long)n0 * DIM, DIM, 0, acc);
#pragma unroll
  for (int mi = 0; mi < 4; ++mi) {
    int n = n0 + l16;
#pragma unroll
    for (int r = 0; r < 4; ++r) {
      int s = m * 64 + mi * 16 + quad * 4 + r;
      float y = tanhf(acc[mi][0][r]);
      long idx = (long)s * DIM + n;
      yout[idx] = y;
      ywm_bf[idx] = f2bf(y);
    }
  }
}

// ---------------------------------------------------------------------------
// K4/K6: a = cur@W_x^T + h@W_h^T + y_wm@W_wml^T
// 256 blocks x 64 threads: m = blk&3, nt = blk>>2 (64 e-tiles: b = nt>>3)
// ---------------------------------------------------------------------------
__global__ __launch_bounds__(64) void k_gemm_a(
    int l, const u16* __restrict__ cur_bf, const u16* __restrict__ h_bf,
    const u16* __restrict__ ywm_bf,
    const float* __restrict__ W_x, const float* __restrict__ W_h,
    const float* __restrict__ W_wml,
    float* __restrict__ a_f32, u16* __restrict__ a_bf)
{
  const int tid = threadIdx.x, quad = tid >> 4, l16 = tid & 15;
  const int m = blockIdx.x & 3;
  const int nt = blockIdx.x >> 2;
  const int b = nt >> 3;
  const int e0 = (nt & 7) * 16;
  ACC_DECL(1)
  const long moff = (long)m * 64 * DIM;
  wave_gemm<4, 1, DH, false>(cur_bf + moff + b * DH, DIM,
                             W_x + ((long)(l * NB + b) * DH + e0) * DH, DH, 0, acc);
  wave_gemm<4, 1, DH, false>(h_bf + (long)l * BSZ * DIM + moff + b * DH, DIM,
                             W_h + ((long)(l * NB + b) * DH + e0) * DH, DH, 0, acc);
  wave_gemm<4, 1, DIM, false>(ywm_bf + moff, DIM,
                              W_wml + ((long)(l * NB + b) * DH + e0) * DIM, DIM, 0, acc);
#pragma unroll
  for (int mi = 0; mi < 4; ++mi) {
    int e = e0 + l16;
#pragma unroll
    for (int r = 0; r < 4; ++r) {
      int s = m * 64 + mi * 16 + quad * 4 + r;
      float c = acc[mi][0][r];
      long idx = (long)s * DIM + b * DH + e;
      a_f32[idx] = c;
      a_bf[idx] = f2bf(c);
    }
  }
}

// ---------------------------------------------------------------------------
// K5/K7: g = sigmoid(a@W_g^T + surprise*w_s + b_g); h_new gating
// ---------------------------------------------------------------------------
__global__ __launch_bounds__(64) void k_gemm_g(
    int l, const u16* __restrict__ a_bf, const float* __restrict__ W_g,
    const float* __restrict__ w_s, const float* __restrict__ b_g,
    const float* __restrict__ surprise, const float* __restrict__ carry,
    const float* __restrict__ hstate, const float* __restrict__ a_f32,
    u16* __restrict__ hout_bf)
{
  const int tid = threadIdx.x, quad = tid >> 4, l16 = tid & 15;
  const int m = blockIdx.x & 3;
  const int nt = blockIdx.x >> 2;
  const int b = nt >> 3;
  const int e0 = (nt & 7) * 16;
  ACC_DECL(1)
  wave_gemm<4, 1, DH, false>(a_bf + (long)m * 64 * DIM + b * DH, DIM,
                             W_g + ((long)(l * NB + b) * DH + e0) * DH, DH, 0, acc);
#pragma unroll
  for (int mi = 0; mi < 4; ++mi) {
    int e = e0 + l16;
#pragma unroll
    for (int r = 0; r < 4; ++r) {
      int s = m * 64 + mi * 16 + quad * 4 + r;
      float c = acc[mi][0][r];
      long idx = (long)s * DIM + b * DH + e;
      float gp = c + surprise[s] * w_s[(l * NB + b) * DH + e] + b_g[(l * NB + b) * DH + e];
      float g = sigm(gp);
      float ho = hstate[(long)l * BSZ * DIM + idx];
      float hn = carry[s] * ((1.0f - g) * ho + g * tanhf(a_f32[idx]));
      hout_bf[idx] = f2bf(hn);
    }
  }
}

// ---------------------------------------------------------------------------
// K8: logits = h_final @ emb^T — counted-vmcnt pipeline (T4), raw s_barrier.
// 786 blocks x 256 threads (4 waves), 64 vocab cols x 64 K per tile,
// THREE 16 KB LDS buffers, STAGE issued 2 tiles ahead, ONE raw barrier per
// tile, NEVER a vmcnt(0) drain in the loop.
//
// R4 post-mortem: __syncthreads drains vmcnt(0), flattening any DMA
// lookahead every iteration (the guide's structural ~20%-stall, but here
// compute is small so it was ~70%). Fix: raw `s_barrier` via asm (memory
// clobber + sched_barrier fences), and ISSUE ORDER A-loads -> STAGE(t+2)
// -> compute. The compiler's own pre-MFMA wait for the A frags then emits
// vmcnt(4) (only STAGE(t+2)'s 4 DMAs are younger), which by in-order
// vmem retirement proves D(t+1) complete for the next barrier while
// leaving D(t+2) in flight with ~1.3 iterations of latency cover.
//
// Race audit (one barrier per tile, 3 buffers):
//  - read-after-DMA: wave-local vmcnt proves own D(t+1) done before
//    barrier t+1; barrier release => all waves' D(t+1) landed.
//  - write-after-read: STAGE(t+2)->buf[(t+2)%3]=buf[(t-1)%3], whose reads
//    (iter t-1) are sealed by barrier t, which precedes the STAGE issue.
//  - sched_barrier(0) around each s_barrier keeps ds_reads from hoisting
//    above the barrier (they'd race other waves' DMAs; rule #18 analog).
// ---------------------------------------------------------------------------
__global__ __launch_bounds__(256, 3) void k_logits_p3(
    const u16* __restrict__ hfin_bf, const float* __restrict__ emb,
    float* __restrict__ out)
{
  __shared__ float Bs[3][64 * 64];        // 3 x 16 KB f32 tiles
  const int tid  = threadIdx.x;
  const int wave = tid >> 6;
  const int lane = tid & 63;
  const int quad = lane >> 4;
  const int l16  = lane & 15;
  const int n0   = blockIdx.x * 64;

  // staging: wave w owns LDS rows w*16..+15; DMA j covers rows w*16+j*4..+3.
  // lane -> (row = base + lane>>4, chunk = lane&15); HW dest = base + lane*16.
  const float* srcP[4];
#pragma unroll
  for (int j = 0; j < 4; ++j) {
    int r = wave * 16 + j * 4 + (lane >> 4);
    int c = (lane & 15) ^ (r & 15);       // inverse swizzle on the source
    long gn = n0 + r; if (gn > VOC - 1) gn = VOC - 1;  // tail clamp (dups discarded)
    srcP[j] = emb + gn * DIM + c * 4;
  }

  const u16* aP[4];
#pragma unroll
  for (int mi = 0; mi < 4; ++mi)
    aP[mi] = hfin_bf + (long)(wave * 64 + mi * 16 + l16) * DIM + quad * 8;

  f32x4 acc[4][4];
  { f32x4 z = {0.f, 0.f, 0.f, 0.f};
#pragma unroll
    for (int mi = 0; mi < 4; ++mi)
#pragma unroll
      for (int ni = 0; ni < 4; ++ni) acc[mi][ni] = z; }

#define STAGE(bufi, t)                                                    \
  { float* d = &Bs[bufi][wave * 1024];                                    \
    _Pragma("unroll")                                                     \
    for (int j = 0; j < 4; ++j)                                           \
      gld16(srcP[j] + (t) * 64, d + j * 256); }

#define RAWBAR()                                                          \
  { __builtin_amdgcn_sched_barrier(0);                                    \
    asm volatile("s_barrier" ::: "memory");                               \
    __builtin_amdgcn_sched_barrier(0); }

  // prologue: D(0), D(1); wait D(0) only (4 younger DMAs outstanding)
  STAGE(0, 0)
  STAGE(1, 1)
  asm volatile("s_waitcnt vmcnt(4)" ::: "memory");
  RAWBAR()

  const int NT = DIM / 64;                // 16
#pragma unroll 1
  for (int t = 0; t < NT; ++t) {
    const int k0 = t * 64;
    // A frags FIRST (their compiler-wait counts only the 4 younger DMAs)
    bf16x8 aF0[4], aF1[4];
#pragma unroll
    for (int mi = 0; mi < 4; ++mi) aF0[mi] = *(const bf16x8*)(aP[mi] + k0);
#pragma unroll
    for (int mi = 0; mi < 4; ++mi) aF1[mi] = *(const bf16x8*)(aP[mi] + k0 + 32);
    if (t + 2 < NT) { STAGE((t + 2) % 3, t + 2) }

    const char* bb = (const char*)&Bs[t % 3][0];
    bf16x8 bF0[4], bF1[4];
#pragma unroll
    for (int ni = 0; ni < 4; ++ni) {
      const char* rb = bb + (ni * 16 + l16) * 256;
      float4 u0 = *(const float4*)(rb + (((quad * 2)     ^ l16) << 4));
      float4 u1 = *(const float4*)(rb + (((quad * 2 + 1) ^ l16) << 4));
      float4 w0 = *(const float4*)(rb + (((quad * 2 + 8) ^ l16) << 4));
      float4 w1 = *(const float4*)(rb + (((quad * 2 + 9) ^ l16) << 4));
      bF0[ni] = cvt8(u0, u1);
      bF1[ni] = cvt8(w0, w1);
    }
#pragma unroll
    for (int mi = 0; mi < 4; ++mi)
#pragma unroll
      for (int ni = 0; ni < 4; ++ni)
        acc[mi][ni] = __builtin_amdgcn_mfma_f32_16x16x32_bf16(
            aF0[mi], bF0[ni], acc[mi][ni], 0, 0, 0);
#pragma unroll
    for (int mi = 0; mi < 4; ++mi)
#pragma unroll
      for (int ni = 0; ni < 4; ++ni)
        acc[mi][ni] = __builtin_amdgcn_mfma_f32_16x16x32_bf16(
            aF1[mi], bF1[ni], acc[mi][ni], 0, 0, 0);

    if (t + 1 < NT) RAWBAR()
  }
#undef STAGE
#undef RAWBAR

#pragma unroll
  for (int mi = 0; mi < 4; ++mi)
#pragma unroll
    for (int ni = 0; ni < 4; ++ni) {
      int n = n0 + ni * 16 + l16;
      if (n < VOC) {
#pragma unroll
        for (int r = 0; r < 4; ++r) {
          int s = wave * 64 + mi * 16 + quad * 4 + r;
          out[(long)s * VOC + n] = acc[mi][ni][r];
        }
      }
    }
}

extern "C" void kernel_launch(void* const* d_in, const int* in_sizes, int n_in,
                              void* d_out, int out_size, void* d_ws, size_t ws_size,
                              hipStream_t stream) {
  const int*   input_id = (const int*)d_in[0];
  const void*  reset    = d_in[1];
  const float* surprise = (const float*)d_in[2];
  const float* wm_state = (const float*)d_in[3];
  const float* h_state  = (const float*)d_in[4];
  const float* emb      = (const float*)d_in[5];
  const float* W_in     = (const float*)d_in[6];
  const float* W_alpha  = (const float*)d_in[7];
  const float* W_wm_out = (const float*)d_in[8];
  const float* W_x      = (const float*)d_in[9];
  const float* W_h      = (const float*)d_in[10];
  const float* W_wml    = (const float*)d_in[11];
  const float* W_g      = (const float*)d_in[12];
  const float* w_s      = (const float*)d_in[13];
  const float* b_g      = (const float*)d_in[14];

  float* out  = (float*)d_out;
  float* xout = out + (size_t)BSZ * VOC;          // x output (fp32, exact)
  float* yout = xout + (size_t)BSZ * DIM;         // y_wm output

  // Scratch lives in the logits region of d_out (only read before k_logits).
  const long SD = (long)BSZ * DIM;                // 262144
  u16* scr    = (u16*)d_out;
  u16* x_bf   = scr;                              // 256x1024
  u16* wm_bf  = scr + SD;
  u16* cur_bf = scr + 2 * SD;
  u16* ywm_bf = scr + 3 * SD;
  u16* h_bf   = scr + 4 * SD;                     // 2x256x1024
  u16* a_bf   = scr + 6 * SD;
  float* a_f32 = (float*)(scr + 8 * SD);          // 256x1024 fp32

  // h_final + carry live OUTSIDE d_out (read while k_logits writes d_out)
  float* carry  = (float*)d_ws;
  u16* hfin_bf  = (u16*)((char*)d_ws + 1024);
  float* sink   = (float*)((char*)d_ws + 600 * 1024);

  k_prep<<<BSZ, 256, 0, stream>>>(input_id, reset, emb, h_state,
                                  W_alpha, W_in, W_wm_out, W_x, W_h, W_wml, W_g,
                                  xout, x_bf, h_bf, carry, sink);
  k_gemm1<<<512, 64, 0, stream>>>(x_bf, W_alpha, W_in, carry, wm_state, xout, wm_bf, cur_bf);
  k_gemm2<<<256, 64, 0, stream>>>(wm_bf, W_wm_out, yout, ywm_bf);
  k_gemm_a<<<256, 64, 0, stream>>>(0, cur_bf, h_bf, ywm_bf, W_x, W_h, W_wml, a_f32, a_bf);
  k_gemm_g<<<256, 64, 0, stream>>>(0, a_bf, W_g, w_s, b_g, surprise, carry, h_state, a_f32, cur_bf);
  k_gemm_a<<<256, 64, 0, stream>>>(1, cur_bf, h_bf, ywm_bf, W_x, W_h, W_wml, a_f32, a_bf);
  k_gemm_g<<<256, 64, 0, stream>>>(1, a_bf, W_g, w_s, b_g, surprise, carry, h_state, a_f32, hfin_bf);
  k_logits_p3<<<(VOC + 63) / 64, 256, 0, stream>>>(hfin_bf, emb, out);
}

// Round 6
// 445.594 us; speedup vs baseline: 1.0286x; 1.0286x over previous
//
#include <hip/hip_runtime.h>
#include <math.h>

#define BSZ 256
#define DIM 1024
#define VOC 50257
#define NL 2
#define NB 8
#define DH 128

typedef __bf16 bf16x8 __attribute__((ext_vector_type(8)));
typedef float  f32x4  __attribute__((ext_vector_type(4)));
typedef unsigned short u16;
typedef unsigned int u32;
typedef u16 u16x8 __attribute__((ext_vector_type(8)));

__device__ __forceinline__ u16 f2bf(float f) {
  unsigned int u = __float_as_uint(f);
  u += 0x7fffu + ((u >> 16) & 1u);   // RNE
  return (u16)(u >> 16);
}
__device__ __forceinline__ float sigm(float x) { return 1.0f / (1.0f + __expf(-x)); }

// f32x8 -> bf16x8, hardware RNE (bit-identical to f2bf)
__device__ __forceinline__ bf16x8 cvt8(float4 a, float4 b) {
  bf16x8 r;
  r[0] = (__bf16)a.x; r[1] = (__bf16)a.y; r[2] = (__bf16)a.z; r[3] = (__bf16)a.w;
  r[4] = (__bf16)b.x; r[5] = (__bf16)b.y; r[6] = (__bf16)b.z; r[7] = (__bf16)b.w;
  return r;
}

// async global->LDS DMA, 16 B per lane; lds dst is wave-uniform base (+lane*16 by HW)
__device__ __forceinline__ void gld16(const float* g, float* l) {
  __builtin_amdgcn_global_load_lds(
      (const __attribute__((address_space(1))) u32*)(g),
      (__attribute__((address_space(3))) u32*)(l), 16, 0, 0);
}

// ---------------------------------------------------------------------------
// Barrier-free per-wave GEMM: acc[M16][N16] += A(bf16, row-major lda) *
// B(fp32, row-major ldb)^T. Fragments loaded directly from global in MFMA
// operand layout. 4-stage register pipeline. Requires K % 128 == 0.
// ---------------------------------------------------------------------------
template<int M16, int N16, int K, bool CLAMPN>
__device__ __forceinline__ void wave_gemm(
    const u16* __restrict__ A, int lda,
    const float* __restrict__ B, int ldb, int nClamp,
    f32x4 (&acc)[M16][N16])
{
  const int lane = threadIdx.x & 63;
  const int quad = lane >> 4;
  const int l16  = lane & 15;

  const u16* aR[M16];
  const float* bR[N16];
#pragma unroll
  for (int mi = 0; mi < M16; ++mi)
    aR[mi] = A + (long)(mi * 16 + l16) * lda + quad * 8;
#pragma unroll
  for (int ni = 0; ni < N16; ++ni) {
    int n = ni * 16 + l16;
    if (CLAMPN) n = n > nClamp ? nClamp : n;   // clamp addr; result discarded
    bR[ni] = B + (long)n * ldb + quad * 8;
  }

  bf16x8 aF[4][M16];
  bf16x8 bF[4][N16];

#define WG_LOAD(kk, buf)                                                  \
  {                                                                       \
    _Pragma("unroll")                                                     \
    for (int ni = 0; ni < N16; ++ni) {                                    \
      float4 v0 = *(const float4*)(bR[ni] + (kk));                        \
      float4 v1 = *(const float4*)(bR[ni] + (kk) + 4);                    \
      u16x8 h;                                                            \
      h[0] = f2bf(v0.x); h[1] = f2bf(v0.y);                               \
      h[2] = f2bf(v0.z); h[3] = f2bf(v0.w);                               \
      h[4] = f2bf(v1.x); h[5] = f2bf(v1.y);                               \
      h[6] = f2bf(v1.z); h[7] = f2bf(v1.w);                               \
      bF[buf][ni] = __builtin_bit_cast(bf16x8, h);                        \
    }                                                                     \
    _Pragma("unroll")                                                     \
    for (int mi = 0; mi < M16; ++mi)                                      \
      aF[buf][mi] = *(const bf16x8*)(aR[mi] + (kk));                      \
  }

#define WG_MM(buf)                                                        \
  {                                                                       \
    _Pragma("unroll")                                                     \
    for (int mi = 0; mi < M16; ++mi)                                      \
      _Pragma("unroll")                                                   \
      for (int ni = 0; ni < N16; ++ni)                                    \
        acc[mi][ni] = __builtin_amdgcn_mfma_f32_16x16x32_bf16(            \
            aF[buf][mi], bF[buf][ni], acc[mi][ni], 0, 0, 0);              \
  }

  WG_LOAD(0, 0);
  WG_LOAD(32, 1);
  WG_LOAD(64, 2);
#pragma unroll 1
  for (int kk = 0; kk < K - 128; kk += 128) {
    WG_LOAD(kk + 96, 3);  WG_MM(0);
    WG_LOAD(kk + 128, 0); WG_MM(1);
    WG_LOAD(kk + 160, 1); WG_MM(2);
    WG_LOAD(kk + 192, 2); WG_MM(3);
  }
  WG_LOAD(K - 32, 3);
  WG_MM(0); WG_MM(1); WG_MM(2); WG_MM(3);
#undef WG_LOAD
#undef WG_MM
}

#define ACC_DECL(N16V)                                \
  f32x4 acc[4][N16V];                                 \
  { f32x4 z = {0.f, 0.f, 0.f, 0.f};                   \
    _Pragma("unroll")                                 \
    for (int i = 0; i < 4; ++i)                       \
      _Pragma("unroll")                               \
      for (int j = 0; j < N16V; ++j) acc[i][j] = z; }

// ---------------------------------------------------------------------------
// K1: carry (bool-layout detect), x gather, h->bf16, + LLC warm of all weights
// ---------------------------------------------------------------------------
__global__ __launch_bounds__(256) void k_prep(
    const int* __restrict__ ids, const void* __restrict__ mask,
    const float* __restrict__ emb, const float* __restrict__ hstate,
    const float* __restrict__ W_alpha, const float* __restrict__ W_in,
    const float* __restrict__ W_wm_out, const float* __restrict__ W_x,
    const float* __restrict__ W_h, const float* __restrict__ W_wml,
    const float* __restrict__ W_g,
    float* __restrict__ xout, u16* __restrict__ x_bf,
    u16* __restrict__ h_bf, float* __restrict__ carry, float* __restrict__ sink)
{
  __shared__ int sInt;
  const int tid = threadIdx.x, s = blockIdx.x;
  if (tid == 0) sInt = 1;
  __syncthreads();
  if (tid < 64) {
    int v = ((const int*)mask)[tid];
    if (v != 0 && v != 1) atomicAnd(&sInt, 0);
  }
  __syncthreads();
  if (tid == 0) {
    int m = sInt ? ((const int*)mask)[s] : (int)((const unsigned char*)mask)[s];
    carry[s] = m ? 0.0f : 1.0f;
  }
  long id = ids[s];
  int k = tid * 4;
  float4 v = *(const float4*)(emb + id * DIM + k);
  *(float4*)(xout + (long)s * DIM + k) = v;
  ushort4 h; h.x = f2bf(v.x); h.y = f2bf(v.y); h.z = f2bf(v.z); h.w = f2bf(v.w);
  *(ushort4*)(x_bf + (long)s * DIM + k) = h;
#pragma unroll
  for (int l = 0; l < NL; ++l) {
    long off = (long)l * BSZ * DIM + (long)s * DIM + k;
    float4 w = *(const float4*)(hstate + off);
    ushort4 o; o.x = f2bf(w.x); o.y = f2bf(w.y); o.z = f2bf(w.z); o.w = f2bf(w.w);
    *(ushort4*)(h_bf + off) = o;
  }
  // ---- LLC warm (loads can't be eliminated; branch never taken) ----
  long gtid = (long)blockIdx.x * 256 + tid;
  long gstride = (long)gridDim.x * 256;
  float acc = 0.f;
  {
    const long nDD = (long)DIM * DIM / 4;       // 1024x1024 f32 -> float4 count
    for (long i = gtid; i < nDD; i += gstride) {
      float4 a = ((const float4*)W_alpha)[i];
      float4 b = ((const float4*)W_in)[i];
      float4 c = ((const float4*)W_wm_out)[i];
      acc += a.x + a.w + b.x + b.w + c.x + c.w;
    }
    const long nS = (long)NL * NB * DH * DH / 4;
    for (long i = gtid; i < nS; i += gstride) {
      float4 a = ((const float4*)W_x)[i];
      float4 b = ((const float4*)W_h)[i];
      float4 c = ((const float4*)W_g)[i];
      acc += a.x + a.w + b.x + b.w + c.x + c.w;
    }
    const long nW = (long)NL * NB * DH * DIM / 4;
    for (long i = gtid; i < nW; i += gstride) {
      float4 a = ((const float4*)W_wml)[i];
      acc += a.x + a.w;
    }
  }
  if (acc == -1.17521e35f) *sink = acc;   // never true in practice; defeats DCE
}

// ---------------------------------------------------------------------------
// K2: [alpha_pre | x_proj] = x @ [W_alpha ; W_in]^T, fused wm_new epilogue
// 512 blocks x 64 threads: m-slice = blk&3, n-tile16 = blk>>2 (128 tiles)
// ---------------------------------------------------------------------------
__global__ __launch_bounds__(64) void k_gemm1(
    const u16* __restrict__ x_bf,
    const float* __restrict__ W_alpha, const float* __restrict__ W_in,
    const float* __restrict__ carry, const float* __restrict__ wm_state,
    const float* __restrict__ xout,
    u16* __restrict__ wm_bf, u16* __restrict__ cur_bf)
{
  const int tid = threadIdx.x, quad = tid >> 4, l16 = tid & 15;
  const int m = blockIdx.x & 3;
  const int nt = blockIdx.x >> 2;
  const bool isAlpha = nt < 64;
  const int n0 = (isAlpha ? nt : nt - 64) * 16;
  ACC_DECL(1)
  wave_gemm<4, 1, DIM, false>(x_bf + (long)m * 64 * DIM, DIM,
                              (isAlpha ? W_alpha : W_in) + (long)n0 * DIM, DIM, 0, acc);
#pragma unroll
  for (int mi = 0; mi < 4; ++mi) {
    int n = n0 + l16;
#pragma unroll
    for (int r = 0; r < 4; ++r) {
      int s = m * 64 + mi * 16 + quad * 4 + r;
      float c = acc[mi][0][r];
      long idx = (long)s * DIM + n;
      if (isAlpha) wm_bf[idx] = f2bf(carry[s] * sigm(c) * wm_state[idx] + xout[idx]);
      else         cur_bf[idx] = f2bf(c);
    }
  }
}

// ---------------------------------------------------------------------------
// K3: y_wm = tanh(wm_new @ W_wm_out^T)   (256 blocks x 64 threads)
// ---------------------------------------------------------------------------
__global__ __launch_bounds__(64) void k_gemm2(
    const u16* __restrict__ wm_bf, const float* __restrict__ W_wm_out,
    float* __restrict__ yout, u16* __restrict__ ywm_bf)
{
  const int tid = threadIdx.x, quad = tid >> 4, l16 = tid & 15;
  const int m = blockIdx.x & 3;
  const int n0 = (blockIdx.x >> 2) * 16;
  ACC_DECL(1)
  wave_gemm<4, 1, DIM, false>(wm_bf + (long)m * 64 * DIM, DIM,
                              W_wm_out + (long)n0 * DIM, DIM, 0, acc);
#pragma unroll
  for (int mi = 0; mi < 4; ++mi) {
    int n = n0 + l16;
#pragma unroll
    for (int r = 0; r < 4; ++r) {
      int s = m * 64 + mi * 16 + quad * 4 + r;
      float y = tanhf(acc[mi][0][r]);
      long idx = (long)s * DIM + n;
      yout[idx] = y;
      ywm_bf[idx] = f2bf(y);
    }
  }
}

// ---------------------------------------------------------------------------
// K4/K6: a = cur@W_x^T + h@W_h^T + y_wm@W_wml^T
// 256 blocks x 64 threads: m = blk&3, nt = blk>>2 (64 e-tiles: b = nt>>3)
// ---------------------------------------------------------------------------
__global__ __launch_bounds__(64) void k_gemm_a(
    int l, const u16* __restrict__ cur_bf, const u16* __restrict__ h_bf,
    const u16* __restrict__ ywm_bf,
    const float* __restrict__ W_x, const float* __restrict__ W_h,
    const float* __restrict__ W_wml,
    float* __restrict__ a_f32, u16* __restrict__ a_bf)
{
  const int tid = threadIdx.x, quad = tid >> 4, l16 = tid & 15;
  const int m = blockIdx.x & 3;
  const int nt = blockIdx.x >> 2;
  const int b = nt >> 3;
  const int e0 = (nt & 7) * 16;
  ACC_DECL(1)
  const long moff = (long)m * 64 * DIM;
  wave_gemm<4, 1, DH, false>(cur_bf + moff + b * DH, DIM,
                             W_x + ((long)(l * NB + b) * DH + e0) * DH, DH, 0, acc);
  wave_gemm<4, 1, DH, false>(h_bf + (long)l * BSZ * DIM + moff + b * DH, DIM,
                             W_h + ((long)(l * NB + b) * DH + e0) * DH, DH, 0, acc);
  wave_gemm<4, 1, DIM, false>(ywm_bf + moff, DIM,
                              W_wml + ((long)(l * NB + b) * DH + e0) * DIM, DIM, 0, acc);
#pragma unroll
  for (int mi = 0; mi < 4; ++mi) {
    int e = e0 + l16;
#pragma unroll
    for (int r = 0; r < 4; ++r) {
      int s = m * 64 + mi * 16 + quad * 4 + r;
      float c = acc[mi][0][r];
      long idx = (long)s * DIM + b * DH + e;
      a_f32[idx] = c;
      a_bf[idx] = f2bf(c);
    }
  }
}

// ---------------------------------------------------------------------------
// K5/K7: g = sigmoid(a@W_g^T + surprise*w_s + b_g); h_new gating
// ---------------------------------------------------------------------------
__global__ __launch_bounds__(64) void k_gemm_g(
    int l, const u16* __restrict__ a_bf, const float* __restrict__ W_g,
    const float* __restrict__ w_s, const float* __restrict__ b_g,
    const float* __restrict__ surprise, const float* __restrict__ carry,
    const float* __restrict__ hstate, const float* __restrict__ a_f32,
    u16* __restrict__ hout_bf)
{
  const int tid = threadIdx.x, quad = tid >> 4, l16 = tid & 15;
  const int m = blockIdx.x & 3;
  const int nt = blockIdx.x >> 2;
  const int b = nt >> 3;
  const int e0 = (nt & 7) * 16;
  ACC_DECL(1)
  wave_gemm<4, 1, DH, false>(a_bf + (long)m * 64 * DIM + b * DH, DIM,
                             W_g + ((long)(l * NB + b) * DH + e0) * DH, DH, 0, acc);
#pragma unroll
  for (int mi = 0; mi < 4; ++mi) {
    int e = e0 + l16;
#pragma unroll
    for (int r = 0; r < 4; ++r) {
      int s = m * 64 + mi * 16 + quad * 4 + r;
      float c = acc[mi][0][r];
      long idx = (long)s * DIM + b * DH + e;
      float gp = c + surprise[s] * w_s[(l * NB + b) * DH + e] + b_g[(l * NB + b) * DH + e];
      float g = sigm(gp);
      float ho = hstate[(long)l * BSZ * DIM + idx];
      float hn = carry[s] * ((1.0f - g) * ho + g * tanhf(a_f32[idx]));
      hout_bf[idx] = f2bf(hn);
    }
  }
}

// ---------------------------------------------------------------------------
// K8: logits = h_final @ emb^T — 128-col tile to amortize A traffic.
//
// R1-R5 model fit: k_logits time ≈ total vmem bytes / (256 CU x ~8-10 B/cy)
// regardless of schedule (R2 reg-staged == R4 gload_lds == R5 counted-vmcnt
// within 5%). The A operand (hfin, 512 KB/block) is re-read by EVERY block:
// at 64 cols that's 402 of 604 MB. 128 cols/block: 393 blocks x (512K A +
// 512K B) = 402 MB total (-33%).
//
// 393 blocks x 256 threads (4 waves), acc[4][8] (128 VGPR), 2 x 32 KB LDS
// f32 buffers (64 KB -> 2 blocks/CU via __launch_bounds__(256,2)). R4's
// proven-correct schedule: STAGE(t+1) before compute, one __syncthreads
// per tile (drains DMA + seals reads). bF convert fused per-ni to cap
// register pressure. Same global-source swizzle; row&15 == l16 holds for
// all ni (ni*16 keeps low 4 bits).
// ---------------------------------------------------------------------------
__global__ __launch_bounds__(256, 2) void k_logits_128(
    const u16* __restrict__ hfin_bf, const float* __restrict__ emb,
    float* __restrict__ out)
{
  __shared__ float Bs[2][128 * 64];       // 2 x 32 KB f32 tiles
  const int tid  = threadIdx.x;
  const int wave = tid >> 6;
  const int lane = tid & 63;
  const int quad = lane >> 4;
  const int l16  = lane & 15;
  const int n0   = blockIdx.x * 128;

  // staging: wave w owns LDS rows w*32..+31; DMA j covers rows w*32+j*4..+3.
  // lane -> (row = base + lane>>4, chunk = (lane&15)^(row&15)); HW dest =
  // wave-uniform base + lane*16.
  const float* srcP[8];
#pragma unroll
  for (int j = 0; j < 8; ++j) {
    int r = wave * 32 + j * 4 + (lane >> 4);
    int c = (lane & 15) ^ (r & 15);       // inverse swizzle on the source
    long gn = n0 + r; if (gn > VOC - 1) gn = VOC - 1;  // tail clamp (dups discarded)
    srcP[j] = emb + gn * DIM + c * 4;
  }

  const u16* aP[4];
#pragma unroll
  for (int mi = 0; mi < 4; ++mi)
    aP[mi] = hfin_bf + (long)(wave * 64 + mi * 16 + l16) * DIM + quad * 8;

  f32x4 acc[4][8];
  { f32x4 z = {0.f, 0.f, 0.f, 0.f};
#pragma unroll
    for (int mi = 0; mi < 4; ++mi)
#pragma unroll
      for (int ni = 0; ni < 8; ++ni) acc[mi][ni] = z; }

#define STAGE(bufi, t)                                                    \
  { float* d = &Bs[bufi][wave * 2048];                                    \
    _Pragma("unroll")                                                     \
    for (int j = 0; j < 8; ++j)                                           \
      gld16(srcP[j] + (t) * 64, d + j * 256); }

  STAGE(0, 0)
  __syncthreads();                        // drain DMA of tile 0

  const int NT = DIM / 64;                // 16
#pragma unroll 1
  for (int t = 0; t < NT; ++t) {
    const int k0 = t * 64;
    // A frags first (compiler's pre-MFMA wait then counts only the 8
    // younger staging DMAs)
    bf16x8 aF0[4], aF1[4];
#pragma unroll
    for (int mi = 0; mi < 4; ++mi) aF0[mi] = *(const bf16x8*)(aP[mi] + k0);
#pragma unroll
    for (int mi = 0; mi < 4; ++mi) aF1[mi] = *(const bf16x8*)(aP[mi] + k0 + 32);
    if (t + 1 < NT) { STAGE((t + 1) & 1, t + 1) }

    const char* bb = (const char*)&Bs[t & 1][0];
#pragma unroll
    for (int ni = 0; ni < 8; ++ni) {
      const char* rb = bb + (ni * 16 + l16) * 256;
      float4 u0 = *(const float4*)(rb + (((quad * 2)     ^ l16) << 4));
      float4 u1 = *(const float4*)(rb + (((quad * 2 + 1) ^ l16) << 4));
      float4 w0 = *(const float4*)(rb + (((quad * 2 + 8) ^ l16) << 4));
      float4 w1 = *(const float4*)(rb + (((quad * 2 + 9) ^ l16) << 4));
      bf16x8 bF0 = cvt8(u0, u1);
      bf16x8 bF1 = cvt8(w0, w1);
#pragma unroll
      for (int mi = 0; mi < 4; ++mi)
        acc[mi][ni] = __builtin_amdgcn_mfma_f32_16x16x32_bf16(
            aF0[mi], bF0, acc[mi][ni], 0, 0, 0);
#pragma unroll
      for (int mi = 0; mi < 4; ++mi)
        acc[mi][ni] = __builtin_amdgcn_mfma_f32_16x16x32_bf16(
            aF1[mi], bF1, acc[mi][ni], 0, 0, 0);
    }

    __syncthreads();   // one barrier/tile: drains next-tile DMA + seals reads
  }
#undef STAGE

#pragma unroll
  for (int mi = 0; mi < 4; ++mi)
#pragma unroll
    for (int ni = 0; ni < 8; ++ni) {
      int n = n0 + ni * 16 + l16;
      if (n < VOC) {
#pragma unroll
        for (int r = 0; r < 4; ++r) {
          int s = wave * 64 + mi * 16 + quad * 4 + r;
          out[(long)s * VOC + n] = acc[mi][ni][r];
        }
      }
    }
}

extern "C" void kernel_launch(void* const* d_in, const int* in_sizes, int n_in,
                              void* d_out, int out_size, void* d_ws, size_t ws_size,
                              hipStream_t stream) {
  const int*   input_id = (const int*)d_in[0];
  const void*  reset    = d_in[1];
  const float* surprise = (const float*)d_in[2];
  const float* wm_state = (const float*)d_in[3];
  const float* h_state  = (const float*)d_in[4];
  const float* emb      = (const float*)d_in[5];
  const float* W_in     = (const float*)d_in[6];
  const float* W_alpha  = (const float*)d_in[7];
  const float* W_wm_out = (const float*)d_in[8];
  const float* W_x      = (const float*)d_in[9];
  const float* W_h      = (const float*)d_in[10];
  const float* W_wml    = (const float*)d_in[11];
  const float* W_g      = (const float*)d_in[12];
  const float* w_s      = (const float*)d_in[13];
  const float* b_g      = (const float*)d_in[14];

  float* out  = (float*)d_out;
  float* xout = out + (size_t)BSZ * VOC;          // x output (fp32, exact)
  float* yout = xout + (size_t)BSZ * DIM;         // y_wm output

  // Scratch lives in the logits region of d_out (only read before k_logits).
  const long SD = (long)BSZ * DIM;                // 262144
  u16* scr    = (u16*)d_out;
  u16* x_bf   = scr;                              // 256x1024
  u16* wm_bf  = scr + SD;
  u16* cur_bf = scr + 2 * SD;
  u16* ywm_bf = scr + 3 * SD;
  u16* h_bf   = scr + 4 * SD;                     // 2x256x1024
  u16* a_bf   = scr + 6 * SD;
  float* a_f32 = (float*)(scr + 8 * SD);          // 256x1024 fp32

  // h_final + carry live OUTSIDE d_out (read while k_logits writes d_out)
  float* carry  = (float*)d_ws;
  u16* hfin_bf  = (u16*)((char*)d_ws + 1024);
  float* sink   = (float*)((char*)d_ws + 600 * 1024);

  k_prep<<<BSZ, 256, 0, stream>>>(input_id, reset, emb, h_state,
                                  W_alpha, W_in, W_wm_out, W_x, W_h, W_wml, W_g,
                                  xout, x_bf, h_bf, carry, sink);
  k_gemm1<<<512, 64, 0, stream>>>(x_bf, W_alpha, W_in, carry, wm_state, xout, wm_bf, cur_bf);
  k_gemm2<<<256, 64, 0, stream>>>(wm_bf, W_wm_out, yout, ywm_bf);
  k_gemm_a<<<256, 64, 0, stream>>>(0, cur_bf, h_bf, ywm_bf, W_x, W_h, W_wml, a_f32, a_bf);
  k_gemm_g<<<256, 64, 0, stream>>>(0, a_bf, W_g, w_s, b_g, surprise, carry, h_state, a_f32, cur_bf);
  k_gemm_a<<<256, 64, 0, stream>>>(1, cur_bf, h_bf, ywm_bf, W_x, W_h, W_wml, a_f32, a_bf);
  k_gemm_g<<<256, 64, 0, stream>>>(1, a_bf, W_g, w_s, b_g, surprise, carry, h_state, a_f32, hfin_bf);
  k_logits_128<<<(VOC + 127) / 128, 256, 0, stream>>>(hfin_bf, emb, out);
}